// Round 2
// baseline (151.696 us; speedup 1.0000x reference)
//
#include <hip/hip_runtime.h>
#include <hip/hip_bf16.h>
#include <math.h>

// ---------------------------------------------------------------------------
// SAContrastiveAdversarialLoss on MI355X (gfx950)
// B=8192, D=128, S=64. Output: scalar fp32.
//
// loss = sum_i -log(1e-12 + num_i/denom_i) / (B*(2B-1))
//        + sum_i -log(1e-12 + 1 - picked_i)
// num_i   = exp(10*cos(z1_i, z2_i))
// denom_i = sum_k exp(10*cos(z1_i,z2_k)) + sum_k exp(10*cos(z1_i,z1_k))
//           - exp(10*cos(z1_i,z1_i))
// picked_i = normalize(c_i)[argmax(label_i)]
//
// v3 structure:
//  - prep: fragment-tiled A/K scatter (unchanged from v2, measured cheap).
//  - main: block = 128 rows x 512 cols, 4 waves share B tiles (L1 reuse);
//    2 row-strips/wave (afrag 32 regs) + launch_bounds(256,5) -> ~5 waves/SIMD
//    for latency hiding; NO atomics -- per-chunk partials stored to T2[row][32]
//    (plain stores, removes 17 MB atomic write-through + serialization).
//  - final_adv: 64 blocks x grid-stride; reduces T2 partials in the same
//    64-lane butterfly as the adversarial argmax; ONE same-address atomic per
//    block (64 total vs 2048 -- the suspected hidden ~70 us serialization).
// ---------------------------------------------------------------------------

#define NROWS 8192
#define DFEAT 128

typedef __bf16 bf16_t;
typedef __bf16 bf16x8 __attribute__((ext_vector_type(8)));
typedef __bf16 bf16x2 __attribute__((ext_vector_type(2)));
typedef float  f32x4  __attribute__((ext_vector_type(4)));

__device__ __forceinline__ float fexp2(float x) {
#if __has_builtin(__builtin_amdgcn_exp2f)
  return __builtin_amdgcn_exp2f(x);
#else
  return exp2f(x);
#endif
}

// ---------------------------------------------------------------------------
// prep: one wave per row. Computes row norms + diagonal dots. Writes A and K
// operands in MFMA-fragment-tiled order:
//   frag element index = ((tile*4 + kf)*64 + quad*16 + (row&15))*8 + j
// where tile = key_index>>4, k = kf*32 + quad*8 + j.  A lane covers
// k = 2*lane, 2*lane+1  ->  kf = lane>>4, quad = (lane>>2)&3, j = 2*(lane&3).
// Also zeroes out[0] (row 0).
__global__ __launch_bounds__(256)
void sa_prep_kernel(const float* __restrict__ z1,
                    const float* __restrict__ z2,
                    bf16_t* __restrict__ Abuf,
                    bf16_t* __restrict__ Kc,
                    float* __restrict__ numv,
                    float* __restrict__ d11v,
                    float* __restrict__ out) {
  int wave = threadIdx.x >> 6;
  int lane = threadIdx.x & 63;
  int row  = blockIdx.x * 4 + wave;

  const float2* z1p = (const float2*)(z1 + row * DFEAT);
  const float2* z2p = (const float2*)(z2 + row * DFEAT);
  float2 a = z1p[lane];
  float2 b = z2p[lane];

  float s1  = a.x * a.x + a.y * a.y;
  float s2  = b.x * b.x + b.y * b.y;
  float s12 = a.x * b.x + a.y * b.y;
#pragma unroll
  for (int m = 32; m; m >>= 1) {
    s1  += __shfl_xor(s1, m, 64);
    s2  += __shfl_xor(s2, m, 64);
    s12 += __shfl_xor(s12, m, 64);
  }
  float r1 = 1.0f / fmaxf(sqrtf(s1), 1e-8f);  // COS_EPS
  float r2 = 1.0f / fmaxf(sqrtf(s2), 1e-8f);

  const float SCL = 14.426950408889634f;  // 10 * log2(e), folds /tau + exp2

  bf16x2 av;  av[0] = (bf16_t)(a.x * r1 * SCL); av[1] = (bf16_t)(a.y * r1 * SCL);
  bf16x2 k2v; k2v[0] = (bf16_t)(b.x * r2);      k2v[1] = (bf16_t)(b.y * r2);
  bf16x2 k1v; k1v[0] = (bf16_t)(a.x * r1);      k1v[1] = (bf16_t)(a.y * r1);

  int tile = row >> 4;
  int l15c = row & 15;
  int kf   = lane >> 4;
  int qk   = (lane >> 2) & 3;
  int jj   = (lane & 3) * 2;
  size_t fo = ((size_t)qk * 16 + l15c) * 8 + jj;  // within-tile offset part

  *(bf16x2*)(Abuf + (size_t)(tile * 4 + kf) * 512 + fo)         = av;
  *(bf16x2*)(Kc   + (size_t)(tile * 4 + kf) * 512 + fo)         = k2v;
  *(bf16x2*)(Kc   + (size_t)((512 + tile) * 4 + kf) * 512 + fo) = k1v;

  if (lane == 0) {
    numv[row] = expf(10.0f * s12 * r1 * r2);
    d11v[row] = expf(10.0f * s1 * r1 * r1);
    if (row == 0) out[0] = 0.0f;
  }
}

// ---------------------------------------------------------------------------
// main: fused "row-sum of exp(sim)" over the virtual 8192x16384 matrix.
// Block = 128 rows x 512 cols; wave w owns rows [rowBase, rowBase+32) --
// all 4 waves stream the SAME 16-col B tiles (L1 reuse). B is prefetched
// one tile ahead into alternating register buffers (b0/b1, statically
// indexed). Per tile: 4 coalesced 1KB loads, 8 MFMAs, 8 exp2+add.
// MFMA C/D layout: col=lane&15, row=(lane>>4)*4+reg.
// Partial row-sums (this wave's 512 cols) go to T2[row][by] as plain stores.
__global__ __launch_bounds__(256, 5)
void sa_main_kernel(const bf16_t* __restrict__ Abuf,
                    const bf16_t* __restrict__ Kc,
                    float* __restrict__ T2) {
  int wave = threadIdx.x >> 6;
  int lane = threadIdx.x & 63;
  int quad = lane >> 4;

  // bijective XCD swizzle: 2048 blocks, 8 XCDs, 256 blocks each. Each XCD
  // sweeps 4 col-chunks (4 x 128KB of Kc) + all of A (2MB) -> L2-resident.
  int id     = blockIdx.x;
  int xcd    = id & 7;
  int within = id >> 3;                 // 0..255
  int by     = xcd * 4 + (within >> 6); // 0..31  col-chunk: 512 cols
  int bx     = within & 63;             // 0..63  row-block: 128 rows
  int rowBase = (bx * 4 + wave) * 32;
  int colBase = by * 512;

  // A fragments for this wave's 2 row-strips (tiled layout: consecutive
  // 1KB fragments, fully coalesced).
  const bf16x8* ap = (const bf16x8*)Abuf + (size_t)(rowBase >> 4) * 256 + lane;
  bf16x8 afrag[2][4];
#pragma unroll
  for (int s = 0; s < 2; ++s)
#pragma unroll
    for (int kfi = 0; kfi < 4; ++kfi)
      afrag[s][kfi] = ap[(s * 4 + kfi) * 64];

  f32x4 sums[2];
#pragma unroll
  for (int s = 0; s < 2; ++s) sums[s] = (f32x4){0.f, 0.f, 0.f, 0.f};

  // B stream: tile stride = 256 bf16x8 (4KB); frag stride = 64 (1KB).
  const bf16x8* bp = (const bf16x8*)Kc + (size_t)(colBase >> 4) * 256 + lane;

  bf16x8 b0[4], b1[4];
#pragma unroll
  for (int kfi = 0; kfi < 4; ++kfi) b0[kfi] = bp[kfi * 64];

  auto compute = [&](const bf16x8 (&bf)[4]) {
    __builtin_amdgcn_s_setprio(1);
#pragma unroll
    for (int s = 0; s < 2; ++s) {
      f32x4 c = {0.f, 0.f, 0.f, 0.f};
#pragma unroll
      for (int kfi = 0; kfi < 4; ++kfi)
        c = __builtin_amdgcn_mfma_f32_16x16x32_bf16(afrag[s][kfi], bf[kfi], c,
                                                    0, 0, 0);
#pragma unroll
      for (int r = 0; r < 4; ++r) sums[s][r] += fexp2(c[r]);
    }
    __builtin_amdgcn_s_setprio(0);
  };

  // 32 tiles, software-pipelined 2-deep with named buffers (no runtime
  // buffer index -> stays in registers).
#pragma unroll 1
  for (int it = 0; it < 15; ++it) {
#pragma unroll
    for (int kfi = 0; kfi < 4; ++kfi) b1[kfi] = bp[256 + kfi * 64];
    compute(b0);
    bp += 512;
#pragma unroll
    for (int kfi = 0; kfi < 4; ++kfi) b0[kfi] = bp[kfi * 64];
    compute(b1);
  }
#pragma unroll
  for (int kfi = 0; kfi < 4; ++kfi) b1[kfi] = bp[256 + kfi * 64];
  compute(b0);
  compute(b1);

  // Reduce across the 16 lanes of each quad-group (cols), then one lane
  // per quad commits 4 row partial-sums with plain stores (no atomics).
  int l15 = lane & 15;
#pragma unroll
  for (int s = 0; s < 2; ++s) {
#pragma unroll
    for (int r = 0; r < 4; ++r) {
      float v = sums[s][r];
      v += __shfl_xor(v, 1, 64);
      v += __shfl_xor(v, 2, 64);
      v += __shfl_xor(v, 4, 64);
      v += __shfl_xor(v, 8, 64);
      if (l15 == 0)
        T2[(size_t)(rowBase + s * 16 + quad * 4 + r) * 32 + by] = v;
    }
  }
}

// ---------------------------------------------------------------------------
// final+adv fused: 64 blocks x 256 threads, grid-stride (32 rows per wave).
// Reduces the 32 T2 partials per row inside the same 64-lane butterfly used
// for the adversarial argmax. One same-address atomicAdd per BLOCK (64 total).
__global__ __launch_bounds__(256)
void sa_final_adv_kernel(const float* __restrict__ T2,
                         const float* __restrict__ numv,
                         const float* __restrict__ d11v,
                         const float* __restrict__ c,
                         const float* __restrict__ lab,
                         float* __restrict__ out) {
  int wave = threadIdx.x >> 6;
  int lane = threadIdx.x & 63;
  int wg   = blockIdx.x * 4 + wave;  // 0..255

  float acc = 0.0f;
#pragma unroll 1
  for (int i = 0; i < 32; ++i) {
    int row = wg + 256 * i;

    float cv = c[row * 64 + lane];
    float lv = lab[row * 64 + lane];
    float tv = (lane < 32) ? T2[(size_t)row * 32 + lane] : 0.0f;

    float ss = cv * cv;
    float bestv = lv;
    int   besti = lane;
#pragma unroll
    for (int m = 32; m; m >>= 1) {
      ss += __shfl_xor(ss, m, 64);
      tv += __shfl_xor(tv, m, 64);
      float ov = __shfl_xor(bestv, m, 64);
      int   oi = __shfl_xor(besti, m, 64);
      if (ov > bestv || (ov == bestv && oi < besti)) { bestv = ov; besti = oi; }
    }
    float picked = __shfl(cv, besti, 64) / fmaxf(sqrtf(ss), 1e-12f);

    if (lane == 0) {
      float denom = tv - d11v[row];  // tv = full row sum of both exp blocks
      acc += -logf(1e-12f + numv[row] / denom) * (1.0f / 134209536.0f)
             - logf(1e-12f + 1.0f - picked);  // LAM = 1
    }
  }

  __shared__ float wacc[4];
  if (lane == 0) wacc[wave] = acc;
  __syncthreads();
  if (threadIdx.x == 0)
    atomicAdd(out, wacc[0] + wacc[1] + wacc[2] + wacc[3]);
}

// ---------------------------------------------------------------------------
extern "C" void kernel_launch(void* const* d_in, const int* in_sizes, int n_in,
                              void* d_out, int out_size, void* d_ws,
                              size_t ws_size, hipStream_t stream) {
  const float* z1  = (const float*)d_in[0];  // [8192,128]
  const float* z2  = (const float*)d_in[1];  // [8192,128]
  const float* co  = (const float*)d_in[2];  // [8192,64]
  const float* lab = (const float*)d_in[3];  // [8192,64]
  float* out = (float*)d_out;

  char* ws = (char*)d_ws;
  bf16_t* Abuf = (bf16_t*)ws;                            // 8192*128*2 = 2 MB
  bf16_t* Kc   = (bf16_t*)(ws + 2u * 1024 * 1024);       // 16384*128*2 = 4 MB
  float*  T2   = (float*)(ws + 6u * 1024 * 1024);        // 8192*32*4 = 1 MB
  float*  numv = (float*)(ws + 7u * 1024 * 1024);        // 32 KB
  float*  d11v = numv + NROWS;                           // 32 KB

  sa_prep_kernel<<<NROWS / 4, 256, 0, stream>>>(z1, z2, Abuf, Kc, numv, d11v,
                                                out);
  sa_main_kernel<<<2048, 256, 0, stream>>>(Abuf, Kc, T2);
  sa_final_adv_kernel<<<64, 256, 0, stream>>>(T2, numv, d11v, co, lab, out);
}

// Round 3
// 111.500 us; speedup vs baseline: 1.3605x; 1.3605x over previous
//
#include <hip/hip_runtime.h>
#include <hip/hip_bf16.h>
#include <math.h>

// ---------------------------------------------------------------------------
// SAContrastiveAdversarialLoss on MI355X (gfx950)
// B=8192, D=128, S=64. Output: scalar fp32.
//
// loss = sum_i -log(1e-12 + num_i/denom_i) / (B*(2B-1))
//        + sum_i -log(1e-12 + 1 - picked_i)
//
// v4 structure:
//  - prep: fragment-tiled A/K scatter (unchanged).
//  - main: 256 rows x 512 cols per block; B staged tile-by-tile into LDS via
//    global_load_lds (fragment layout is exactly lane*16-linear), minimal
//    2-phase pipeline: stage(t+1) || compute(t), vmcnt(0)+raw s_barrier per
//    tile. 4 row-strips/wave (16 MFMA per 4KB tile). No atomics (T2 stores).
//  - final_adv: 2048 blocks, one row/wave, fully parallel; block partial via
//    plain store. sa_reduce (1 block) sums the 2048 partials -> out.
// ---------------------------------------------------------------------------

#define NROWS 8192
#define DFEAT 128

typedef __bf16 bf16_t;
typedef __bf16 bf16x8 __attribute__((ext_vector_type(8)));
typedef __bf16 bf16x2 __attribute__((ext_vector_type(2)));
typedef float  f32x4  __attribute__((ext_vector_type(4)));

__device__ __forceinline__ float fexp2(float x) {
#if __has_builtin(__builtin_amdgcn_exp2f)
  return __builtin_amdgcn_exp2f(x);
#else
  return exp2f(x);
#endif
}

// async global->LDS, 16B per lane. gsrc is per-lane (includes +lane*16);
// lds dst is wave-uniform base (HW adds lane*16).
__device__ __forceinline__ void stage16(const void* gsrc, void* ldst) {
  __builtin_amdgcn_global_load_lds(
      (const __attribute__((address_space(1))) unsigned int*)gsrc,
      (__attribute__((address_space(3))) unsigned int*)ldst, 16, 0, 0);
}

// ---------------------------------------------------------------------------
// prep: one wave per row. Computes row norms + diagonal dots. Writes A and K
// operands in MFMA-fragment-tiled order:
//   frag element index = ((tile*4 + kf)*64 + quad*16 + (row&15))*8 + j
// where tile = key_index>>4, k = kf*32 + quad*8 + j.  A lane covers
// k = 2*lane, 2*lane+1  ->  kf = lane>>4, quad = (lane>>2)&3, j = 2*(lane&3).
__global__ __launch_bounds__(256)
void sa_prep_kernel(const float* __restrict__ z1,
                    const float* __restrict__ z2,
                    bf16_t* __restrict__ Abuf,
                    bf16_t* __restrict__ Kc,
                    float* __restrict__ numv,
                    float* __restrict__ d11v) {
  int wave = threadIdx.x >> 6;
  int lane = threadIdx.x & 63;
  int row  = blockIdx.x * 4 + wave;

  const float2* z1p = (const float2*)(z1 + row * DFEAT);
  const float2* z2p = (const float2*)(z2 + row * DFEAT);
  float2 a = z1p[lane];
  float2 b = z2p[lane];

  float s1  = a.x * a.x + a.y * a.y;
  float s2  = b.x * b.x + b.y * b.y;
  float s12 = a.x * b.x + a.y * b.y;
#pragma unroll
  for (int m = 32; m; m >>= 1) {
    s1  += __shfl_xor(s1, m, 64);
    s2  += __shfl_xor(s2, m, 64);
    s12 += __shfl_xor(s12, m, 64);
  }
  float r1 = 1.0f / fmaxf(sqrtf(s1), 1e-8f);  // COS_EPS
  float r2 = 1.0f / fmaxf(sqrtf(s2), 1e-8f);

  const float SCL = 14.426950408889634f;  // 10 * log2(e), folds /tau + exp2

  bf16x2 av;  av[0] = (bf16_t)(a.x * r1 * SCL); av[1] = (bf16_t)(a.y * r1 * SCL);
  bf16x2 k2v; k2v[0] = (bf16_t)(b.x * r2);      k2v[1] = (bf16_t)(b.y * r2);
  bf16x2 k1v; k1v[0] = (bf16_t)(a.x * r1);      k1v[1] = (bf16_t)(a.y * r1);

  int tile = row >> 4;
  int l15c = row & 15;
  int kf   = lane >> 4;
  int qk   = (lane >> 2) & 3;
  int jj   = (lane & 3) * 2;
  size_t fo = ((size_t)qk * 16 + l15c) * 8 + jj;  // within-tile offset part

  *(bf16x2*)(Abuf + (size_t)(tile * 4 + kf) * 512 + fo)         = av;
  *(bf16x2*)(Kc   + (size_t)(tile * 4 + kf) * 512 + fo)         = k2v;
  *(bf16x2*)(Kc   + (size_t)((512 + tile) * 4 + kf) * 512 + fo) = k1v;

  if (lane == 0) {
    numv[row] = expf(10.0f * s12 * r1 * r2);
    d11v[row] = expf(10.0f * s1 * r1 * r1);
  }
}

// ---------------------------------------------------------------------------
// main: fused "row-sum of exp(sim)" over the virtual 8192x16384 matrix.
// Block = 256 rows x 512 cols; wave w owns rows [bx*256 + w*64, +64).
// Per 16-col tile (4KB of Kc): staged ONCE into LDS (each wave stages 1KB
// via one global_load_lds_dwordx4), then all 4 waves ds_read their frags.
// Minimal 2-phase pipeline: stage(t+1); read+compute(t); vmcnt(0); barrier.
// MFMA C/D layout: col=lane&15, row=(lane>>4)*4+reg.
// Partial row-sums (512 cols) -> T2[row][by] as plain stores (no atomics).
__global__ __launch_bounds__(256, 4)
void sa_main_kernel(const bf16_t* __restrict__ Abuf,
                    const bf16_t* __restrict__ Kc,
                    float* __restrict__ T2) {
  __shared__ __align__(16) bf16_t bsm[2][2048];  // double-buffered 4KB tiles

  int wave = threadIdx.x >> 6;
  int lane = threadIdx.x & 63;
  int quad = lane >> 4;

  // bijective XCD swizzle: 1024 blocks, 8 XCDs, 128 each. Each XCD sweeps
  // 4 col-chunks (512KB of Kc) + all of A (2MB) -> L2-resident.
  int id  = blockIdx.x;
  int swz = (id & 7) * 128 + (id >> 3);
  int bx  = swz & 31;   // row-block: 256 rows
  int by  = swz >> 5;   // col-chunk: 512 cols
  int rowBase = bx * 256 + wave * 64;
  int colBase = by * 512;

  // A fragments for this wave's 4 row-strips (fragment-tiled: consecutive
  // 1KB fragments, fully coalesced 16B/lane).
  const bf16x8* ap = (const bf16x8*)Abuf + (size_t)(rowBase >> 4) * 256 + lane;
  bf16x8 afrag[4][4];
#pragma unroll
  for (int s = 0; s < 4; ++s)
#pragma unroll
    for (int kfi = 0; kfi < 4; ++kfi)
      afrag[s][kfi] = ap[(s * 4 + kfi) * 64];

  f32x4 sums[4];
#pragma unroll
  for (int s = 0; s < 4; ++s) sums[s] = (f32x4){0.f, 0.f, 0.f, 0.f};

  // B stage source: tile t (16 cols) = 4KB at chunk-byte-base + t*4096.
  // Wave w stages fragment w (1KB): +w*1024 + lane*16.
  const char* bsrc = (const char*)Kc + (size_t)(colBase >> 4) * 4096 +
                     (size_t)wave * 1024 + (size_t)lane * 16;
  char* l0 = (char*)&bsm[0][0] + wave * 1024;  // wave-uniform LDS dst
  char* l1 = (char*)&bsm[1][0] + wave * 1024;

  // prologue: stage tile 0, drain, rendezvous.
  stage16(bsrc, l0);
  asm volatile("s_waitcnt vmcnt(0)" ::: "memory");
  __builtin_amdgcn_s_barrier();
  __builtin_amdgcn_sched_barrier(0);

#pragma unroll 1
  for (int it = 0; it < 32; ++it) {
    // stage next tile into the other buffer (overlaps this tile's compute)
    if (it + 1 < 32)
      stage16(bsrc + (size_t)(it + 1) * 4096, (it & 1) ? l0 : l1);

    // read this tile's 4 k-fragments from LDS (linear, conflict-free)
    const bf16x8* bs = (const bf16x8*)&bsm[it & 1][0];
    bf16x8 bfr[4];
#pragma unroll
    for (int kfi = 0; kfi < 4; ++kfi) bfr[kfi] = bs[kfi * 64 + lane];

#pragma unroll
    for (int s = 0; s < 4; ++s) {
      f32x4 c = {0.f, 0.f, 0.f, 0.f};
#pragma unroll
      for (int kfi = 0; kfi < 4; ++kfi)
        c = __builtin_amdgcn_mfma_f32_16x16x32_bf16(afrag[s][kfi], bfr[kfi], c,
                                                    0, 0, 0);
#pragma unroll
      for (int r = 0; r < 4; ++r) sums[s][r] += fexp2(c[r]);
    }

    // drain the in-flight stage (covered by the compute above), rendezvous:
    // next iter may read the other buffer and overwrite this one.
    asm volatile("s_waitcnt vmcnt(0)" ::: "memory");
    __builtin_amdgcn_s_barrier();
    __builtin_amdgcn_sched_barrier(0);
  }

  // Reduce across the 16 lanes of each quad-group (cols), then one lane
  // per quad commits 4 row partial-sums with plain stores (no atomics).
  int l15 = lane & 15;
#pragma unroll
  for (int s = 0; s < 4; ++s) {
#pragma unroll
    for (int r = 0; r < 4; ++r) {
      float v = sums[s][r];
      v += __shfl_xor(v, 1, 64);
      v += __shfl_xor(v, 2, 64);
      v += __shfl_xor(v, 4, 64);
      v += __shfl_xor(v, 8, 64);
      if (l15 == 0)
        T2[(size_t)(rowBase + s * 16 + quad * 4 + r) * 32 + by] = v;
    }
  }
}

// ---------------------------------------------------------------------------
// final+adv fused: 2048 blocks x 256 threads, one row per wave, fully
// parallel. Reduces the 32 T2 partials per row inside the same 64-lane
// butterfly as the adversarial argmax. Block partial -> plain store.
__global__ __launch_bounds__(256)
void sa_final_adv_kernel(const float* __restrict__ T2,
                         const float* __restrict__ numv,
                         const float* __restrict__ d11v,
                         const float* __restrict__ c,
                         const float* __restrict__ lab,
                         float* __restrict__ partial) {
  int wave = threadIdx.x >> 6;
  int lane = threadIdx.x & 63;
  int row  = blockIdx.x * 4 + wave;

  float cv = c[row * 64 + lane];
  float lv = lab[row * 64 + lane];
  float tv = (lane < 32) ? T2[(size_t)row * 32 + lane] : 0.0f;

  float ss = cv * cv;
  float bestv = lv;
  int   besti = lane;
#pragma unroll
  for (int m = 32; m; m >>= 1) {
    ss += __shfl_xor(ss, m, 64);
    tv += __shfl_xor(tv, m, 64);
    float ov = __shfl_xor(bestv, m, 64);
    int   oi = __shfl_xor(besti, m, 64);
    if (ov > bestv || (ov == bestv && oi < besti)) { bestv = ov; besti = oi; }
  }
  float picked = __shfl(cv, besti, 64) / fmaxf(sqrtf(ss), 1e-12f);

  float term = 0.0f;
  if (lane == 0) {
    float denom = tv - d11v[row];  // tv = full row sum of both exp blocks
    term = -logf(1e-12f + numv[row] / denom) * (1.0f / 134209536.0f)
           - logf(1e-12f + 1.0f - picked);  // LAM = 1
  }

  __shared__ float wacc[4];
  if (lane == 0) wacc[wave] = term;
  __syncthreads();
  if (threadIdx.x == 0)
    partial[blockIdx.x] = wacc[0] + wacc[1] + wacc[2] + wacc[3];
}

// ---------------------------------------------------------------------------
// reduce: single block sums the 2048 block partials -> out (plain store).
__global__ __launch_bounds__(256)
void sa_reduce_kernel(const float* __restrict__ partial,
                      float* __restrict__ out) {
  float v = 0.0f;
#pragma unroll
  for (int i = 0; i < 8; ++i) v += partial[threadIdx.x + 256 * i];
#pragma unroll
  for (int m = 32; m; m >>= 1) v += __shfl_xor(v, m, 64);
  __shared__ float wacc[4];
  if ((threadIdx.x & 63) == 0) wacc[threadIdx.x >> 6] = v;
  __syncthreads();
  if (threadIdx.x == 0) out[0] = wacc[0] + wacc[1] + wacc[2] + wacc[3];
}

// ---------------------------------------------------------------------------
extern "C" void kernel_launch(void* const* d_in, const int* in_sizes, int n_in,
                              void* d_out, int out_size, void* d_ws,
                              size_t ws_size, hipStream_t stream) {
  const float* z1  = (const float*)d_in[0];  // [8192,128]
  const float* z2  = (const float*)d_in[1];  // [8192,128]
  const float* co  = (const float*)d_in[2];  // [8192,64]
  const float* lab = (const float*)d_in[3];  // [8192,64]
  float* out = (float*)d_out;

  char* ws = (char*)d_ws;
  bf16_t* Abuf  = (bf16_t*)ws;                           // 8192*128*2 = 2 MB
  bf16_t* Kc    = (bf16_t*)(ws + 2u * 1024 * 1024);      // 16384*128*2 = 4 MB
  float*  T2    = (float*)(ws + 6u * 1024 * 1024);       // 8192*32*4 = 1 MB
  float*  numv  = (float*)(ws + 7u * 1024 * 1024);       // 32 KB
  float*  d11v  = numv + NROWS;                          // 32 KB
  float*  part  = d11v + NROWS;                          // 8 KB

  sa_prep_kernel<<<NROWS / 4, 256, 0, stream>>>(z1, z2, Abuf, Kc, numv, d11v);
  sa_main_kernel<<<1024, 256, 0, stream>>>(Abuf, Kc, T2);
  sa_final_adv_kernel<<<NROWS / 4, 256, 0, stream>>>(T2, numv, d11v, co, lab,
                                                     part);
  sa_reduce_kernel<<<1, 256, 0, stream>>>(part, out);
}